// Round 16
// baseline (313.332 us; speedup 1.0000x reference)
//
#include <hip/hip_runtime.h>
#include <hip/hip_bf16.h>

// B=4, L=2048, DIM=512, H=8, D=64, fp32 in/out.
// pack fp32->fp16 (log2e folded into wq) -> fused QKV MFMA GEMM (BK=64, V^T
// via in-LDS transpose epilogue) -> 32x32x16-MFMA flash attn (64q/wave,
// 4-way key-split, K-frags DIRECT FROM GLOBAL/L2, V double-buffered 2x16KB
// [1 barrier/round], permlane32_swap P-transform, fdot2 lsum) -> out GEMM.
// NOTE: global_load_lds imm offset applies to the GLOBAL address only; the
// LDS dest is always M0 + lane*16 -> multi-call staging must bump BOTH ptrs.

#define Bsz 4
#define Lsz 2048
#define DIMsz 512
#define Hsz 8
#define Dsz 64

typedef _Float16 f16;
typedef __attribute__((ext_vector_type(8))) _Float16 f16x8;
typedef __attribute__((ext_vector_type(4))) _Float16 f16x4;
typedef __attribute__((ext_vector_type(2))) __fp16 fp16x2;  // builtin ret type
typedef __attribute__((ext_vector_type(4))) float f32x4;
typedef __attribute__((ext_vector_type(16))) float f32x16;
typedef unsigned int u32;
typedef __attribute__((ext_vector_type(2))) unsigned int u32x2;

#if __has_builtin(__builtin_amdgcn_exp2f)
#define EXP2(x) __builtin_amdgcn_exp2f(x)
#else
#define EXP2(x) __expf(0.6931471805599453f * (x))
#endif

__device__ __forceinline__ u32 pack2(float a, float b) {
#if __has_builtin(__builtin_amdgcn_cvt_pkrtz)
    fp16x2 h = __builtin_amdgcn_cvt_pkrtz(a, b);
    return __builtin_bit_cast(u32, h);
#else
    fp16x2 h; h.x = (__fp16)a; h.y = (__fp16)b;
    return __builtin_bit_cast(u32, h);
#endif
}

// lsum += p0 + p1 from a packed f16 pair (v_dot2_f32_f16 with ones).
__device__ __forceinline__ float addpair(u32 p, float c) {
#if __has_builtin(__builtin_amdgcn_fdot2)
    fp16x2 ones; ones.x = (__fp16)1.0f; ones.y = (__fp16)1.0f;
    return __builtin_amdgcn_fdot2(__builtin_bit_cast(fp16x2, p), ones, c, false);
#else
    fp16x2 h = __builtin_bit_cast(fp16x2, p);
    return c + (float)h.x + (float)h.y;
#endif
}

// Cross-half exchange for the 32x32 C->B P-transform.
#if __has_builtin(__builtin_amdgcn_permlane32_swap)
__device__ __forceinline__ void plswap(u32& a, u32& b) {
    u32x2 r = __builtin_amdgcn_permlane32_swap(a, b, false, false);
    a = r.x; b = r.y;
}
#else
__device__ __forceinline__ void plswap(u32& a, u32& b) {
    u32 sa = (u32)__shfl_xor((int)a, 32);
    u32 sb = (u32)__shfl_xor((int)b, 32);
    bool hi = (threadIdx.x & 32) != 0;
    u32 na = hi ? sb : a;
    u32 nb = hi ? b : sa;
    a = na; b = nb;
}
#endif

__device__ __forceinline__ void gl2lds16(const void* g, void* l) {
    __builtin_amdgcn_global_load_lds(
        (const __attribute__((address_space(1))) u32*)g,
        (__attribute__((address_space(3))) u32*)l, 16, 0, 0);
}

// ---------------- pack: fp32 -> fp16 ----------------------------------------
__global__ __launch_bounds__(256) void pack_f16(
    const float* __restrict__ x, const float* __restrict__ wq,
    const float* __restrict__ wk, const float* __restrict__ wv,
    const float* __restrict__ wo,
    f16* __restrict__ xh, f16* __restrict__ w3h, f16* __restrict__ woh)
{
    int bx = blockIdx.x, seg, blk;
    if (bx < 4096) { seg = 0; blk = bx; }
    else { seg = 1 + ((bx - 4096) >> 8); blk = (bx - 4096) & 255; }
    const float* s; f16* d; float sc = 1.0f;
    switch (seg) {
        case 0: s = x;  d = xh;            break;
        case 1: s = wq; d = w3h;           sc = 0.18033688011112042f; break;
        case 2: s = wk; d = w3h + 262144;  break;
        case 3: s = wv; d = w3h + 524288;  break;
        default: s = wo; d = woh;          break;
    }
    int i = (blk * 256 + threadIdx.x) * 4;
    float4 v = *(const float4*)(s + i);
    f16x4 o;
    o.x = (f16)(v.x * sc); o.y = (f16)(v.y * sc);
    o.z = (f16)(v.z * sc); o.w = (f16)(v.w * sc);
    *(f16x4*)(d + i) = o;
}

// ---------------- fused QKV MFMA GEMM (BK=64) --------------------------------
__global__ __launch_bounds__(256) void gemm_qkv_f16(
    const f16* __restrict__ A, const f16* __restrict__ B,
    f16* __restrict__ qh, f16* __restrict__ kh, f16* __restrict__ vth)
{
    __shared__ __align__(16) char smem[32768];   // A 16K | B 16K ; Tv reuse
    f16* Ash = (f16*)smem;
    f16* Bsh = (f16*)(smem + 16384);

    const int tid = threadIdx.x;
    const int w = tid >> 6, lane = tid & 63;
    const int quad = lane >> 4, low = lane & 15;
    const int wm = w >> 1, wn = w & 1;
    const int m0 = blockIdx.y * 128, n0 = blockIdx.x * 128;

    f32x4 acc[4][4];
    #pragma unroll
    for (int i = 0; i < 4; i++)
        #pragma unroll
        for (int j = 0; j < 4; j++) acc[i][j] = (f32x4){0.f, 0.f, 0.f, 0.f};

    #pragma unroll 1
    for (int k0 = 0; k0 < DIMsz; k0 += 64) {
        __syncthreads();
        #pragma unroll
        for (int j = 0; j < 4; j++) {
            int t = j * 256 + tid;
            int r = t >> 3, g = t & 7;                 // 128 rows x 8 chunks
            int gc = (g ^ (r & 7)) * 8;
            char* lb = (char*)Ash + (j * 256 + w * 64) * 16;
            gl2lds16(A + (size_t)(m0 + r) * DIMsz + k0 + gc, lb);
            char* lb2 = (char*)Bsh + (j * 256 + w * 64) * 16;
            gl2lds16(B + (size_t)(n0 + r) * DIMsz + k0 + gc, lb2);
        }
        __syncthreads();

        #pragma unroll
        for (int ks2 = 0; ks2 < 2; ks2++) {
            f16x8 af[4], bf[4];
            #pragma unroll
            for (int mt = 0; mt < 4; mt++) {
                int ar = wm * 64 + mt * 16 + low;
                int c = ks2 * 4 + quad;
                af[mt] = *(const f16x8*)&Ash[ar * 64 + ((c ^ (ar & 7)) << 3)];
            }
            #pragma unroll
            for (int nt = 0; nt < 4; nt++) {
                int br = wn * 64 + nt * 16 + low;
                int c = ks2 * 4 + quad;
                bf[nt] = *(const f16x8*)&Bsh[br * 64 + ((c ^ (br & 7)) << 3)];
            }
            #pragma unroll
            for (int mt = 0; mt < 4; mt++)
                #pragma unroll
                for (int nt = 0; nt < 4; nt++)
                    acc[mt][nt] = __builtin_amdgcn_mfma_f32_16x16x32_f16(
                        af[mt], bf[nt], acc[mt][nt], 0, 0, 0);
        }
    }

    const int proj = n0 >> 9;                 // uniform per block
    if (proj < 2) {
        f16* dst = (proj == 0) ? qh : kh;
        #pragma unroll
        for (int nt = 0; nt < 4; nt++) {
            int n = n0 + wn * 64 + nt * 16 + low;
            int c = n & 511, h = c >> 6, d = c & 63;
            #pragma unroll
            for (int mt = 0; mt < 4; mt++)
                #pragma unroll
                for (int r = 0; r < 4; r++) {
                    int m = m0 + wm * 64 + mt * 16 + quad * 4 + r;
                    int b_ = m >> 11, l = m & (Lsz - 1);
                    size_t bh = (size_t)(b_ * Hsz + h);
                    dst[(bh * Lsz + l) * Dsz + d] = (f16)acc[mt][nt][r];
                }
        }
    } else {
        // v: transpose per head through LDS, then coalesced stores
        const int hb = (n0 & 511) >> 6;
        f16* Tv = (f16*)smem;                 // [64 d][136]
        const int b_ = m0 >> 11, l0 = m0 & (Lsz - 1);
        #pragma unroll 1
        for (int hs = 0; hs < 2; hs++) {
            __syncthreads();
            if (wn == hs) {
                #pragma unroll
                for (int nt = 0; nt < 4; nt++) {
                    int d = nt * 16 + low;
                    #pragma unroll
                    for (int mt = 0; mt < 4; mt++)
                        #pragma unroll
                        for (int r = 0; r < 4; r++) {
                            int l = wm * 64 + mt * 16 + quad * 4 + r;
                            Tv[d * 136 + l] = (f16)acc[mt][nt][r];
                        }
                }
            }
            __syncthreads();
            int d = tid >> 2, seg = tid & 3;
            size_t bh = (size_t)(b_ * Hsz + hb + hs);
            f16* dstp = vth + (bh * 64 + d) * (size_t)Lsz + l0 + seg * 32;
            const f16* srcp = Tv + d * 136 + seg * 32;
            #pragma unroll
            for (int j = 0; j < 4; j++)
                *(f16x8*)(dstp + j * 8) = *(const f16x8*)(srcp + j * 8);
        }
    }
}

// ---------------- MFMA flash attention ---------------------------------------
// grid (B*H=32 fastest -> XCD locality, L/64=32), block 256 = 4 waves = 64 q.
// Wave w owns keys w*32..+31 of each 128-key round vs all 64 q. K A-frags
// load DIRECTLY from global (per-head K = 256 KB, XCD-L2-resident); V is
// staged via DMA into a 2x16KB double buffer -> one barrier per round, LDS
// footprint equal to the r14 single-buffer version. 4-way split-K merge at
// the end through the reused V buffers.
__global__ __launch_bounds__(256, 4) void attn_mfma(
    const f16* __restrict__ q, const f16* __restrict__ k,
    const f16* __restrict__ vt, f16* __restrict__ ctx)
{
    __shared__ __align__(16) char smem[32768];   // V dbuf 2x16KB ; O-merge
    __shared__ float Ls[4][2][32];               // per-wave lsum partials

    const int tid = threadIdx.x;
    const int w = tid >> 6, lane = tid & 63;
    const int col = lane & 31;
    const int h = lane >> 5;
    const int bh = blockIdx.x;        // fastest -> heads spread across XCDs
    const int qb = blockIdx.y;
    const int q0 = qb * 64;
    const size_t kvb = (size_t)bh * Lsz;

    // Q B-frags for 2 q-tiles: B[k=d][n=q], lane n=col, k = s*16 + h*8 + j
    f16x8 qf[2][4];
    #pragma unroll
    for (int qt = 0; qt < 2; qt++)
        #pragma unroll
        for (int s = 0; s < 4; s++)
            qf[qt][s] = *(const f16x8*)(q + (kvb + q0 + qt * 32 + col) * Dsz
                                          + s * 16 + h * 8);

    // K global frag base: row w*32+col, byte-col h*16; bumped +128 rows/round
    const f16* kgp = k + (kvb + w * 32 + col) * Dsz + h * 8;

    // V staging source (lane-specific, bumped per round)
    const f16* vp;
    {
        int rv = tid >> 4, gv = tid & 15;         // vp covers rows 0..15
        vp = vt + ((size_t)bh * Dsz + rv) * Lsz + ((gv ^ (rv & 15)) << 3);
    }

    // per-buffer LDS pointers (staging dests + frag reads)
    char* vl[2];
    const f16* vfp[2][2][2];
    #pragma unroll
    for (int b = 0; b < 2; b++) {
        f16* Vs = (f16*)(smem + b * 16384);
        vl[b] = (char*)Vs + (w * 64) * 16;
        #pragma unroll
        for (int dt = 0; dt < 2; dt++)
            #pragma unroll
            for (int ks = 0; ks < 2; ks++) {
                int rv = dt * 32 + col, cv = w * 4 + ks * 2 + h;
                vfp[b][dt][ks] = Vs + rv * 128 + ((cv ^ (rv & 15)) << 3);
            }
    }

    f32x16 acc[2][2];                 // O^T partial [qt][dt], cols = q
    #pragma unroll
    for (int qt = 0; qt < 2; qt++)
        #pragma unroll
        for (int dt = 0; dt < 2; dt++)
            #pragma unroll
            for (int i = 0; i < 16; i++) acc[qt][dt][i] = 0.f;
    float lsum[2] = {0.f, 0.f};

    const int drnd_i = qb >> 1;                   // round containing the diag
    const int dqt = w - (qb & 1) * 2;             // qt this wave diag-masks

    // prologue: stage V round 0 into buf 0
    gl2lds16(vp,            vl[0]);
    gl2lds16(vp + 16 * Lsz, vl[0] + 4096);
    gl2lds16(vp + 32 * Lsz, vl[0] + 8192);
    gl2lds16(vp + 48 * Lsz, vl[0] + 12288);
    vp += 128;
    __syncthreads();

    int b = 0;
    #pragma unroll 1
    for (int r = 0; r < 16; r++) {
        // K frags for this round, straight from global/L2
        f16x8 kf[4];
        #pragma unroll
        for (int s = 0; s < 4; s++)
            kf[s] = *(const f16x8*)(kgp + s * 16);
        kgp += 128 * Dsz;

        // stage next round's V into the other buffer (overlaps compute)
        if (r < 15) {
            char* vnl = vl[b ^ 1];
            gl2lds16(vp,            vnl);
            gl2lds16(vp + 16 * Lsz, vnl + 4096);
            gl2lds16(vp + 32 * Lsz, vnl + 8192);
            gl2lds16(vp + 48 * Lsz, vnl + 12288);
            vp += 128;
        }

        // ---- S^T: A = own 32 K rows, B = both q-tiles; 4 k-steps over d ----
        f32x16 st[2];
        #pragma unroll
        for (int i = 0; i < 16; i++) { st[0][i] = 0.f; st[1][i] = 0.f; }
        #pragma unroll
        for (int s = 0; s < 4; s++) {
            st[0] = __builtin_amdgcn_mfma_f32_32x32x16_f16(kf[s], qf[0][s], st[0], 0, 0, 0);
            st[1] = __builtin_amdgcn_mfma_f32_32x32x16_f16(kf[s], qf[1][s], st[1], 0, 0, 0);
        }

        // ---- softmax numerators + C->B transform per q-tile ----
        union { u32 u[4]; f16x8 v; } pf[2][2];
        const bool drnd = (r == drnd_i);
        #pragma unroll
        for (int qt = 0; qt < 2; qt++) {
            float pv[16];
            #pragma unroll
            for (int i = 0; i < 16; i++) pv[i] = EXP2(st[qt][i]);
            if (drnd && qt == dqt) {
                #pragma unroll
                for (int i = 0; i < 16; i++) {
                    int row = (i & 3) + 8 * (i >> 2) + 4 * h;
                    pv[i] = (row == col) ? 0.f : pv[i];
                }
            }
            u32 P2[8];
            #pragma unroll
            for (int j = 0; j < 8; j++) {
                P2[j] = pack2(pv[2 * j], pv[2 * j + 1]);
                lsum[qt] = addpair(P2[j], lsum[qt]);
            }
            plswap(P2[0], P2[2]); plswap(P2[1], P2[3]);
            plswap(P2[4], P2[6]); plswap(P2[5], P2[7]);
            #pragma unroll
            for (int jj = 0; jj < 4; jj++) {
                pf[qt][0].u[jj] = P2[jj];
                pf[qt][1].u[jj] = P2[4 + jj];
            }
        }

        // ---- O^T += V^T . P over own 32 keys (V frags reused across qt) ----
        #pragma unroll
        for (int dt = 0; dt < 2; dt++)
            #pragma unroll
            for (int ks = 0; ks < 2; ks++) {
                f16x8 vf = *(const f16x8*)vfp[b][dt][ks];
                acc[0][dt] = __builtin_amdgcn_mfma_f32_32x32x16_f16(
                    vf, pf[0][ks].v, acc[0][dt], 0, 0, 0);
                acc[1][dt] = __builtin_amdgcn_mfma_f32_32x32x16_f16(
                    vf, pf[1][ks].v, acc[1][dt], 0, 0, 0);
            }

        __syncthreads();   // drains next-round DMA; all readers done with buf b
        b ^= 1;
    }

    // lsum: reduce over half-wave, publish per-wave partial
    #pragma unroll
    for (int qt = 0; qt < 2; qt++) {
        lsum[qt] += __shfl_xor(lsum[qt], 32);
        if (h == 0) Ls[w][qt][col] = lsum[qt];
    }

    // ---- 4-way split-K merge via reused V buffers (2 x 16KB slots) ----
    float* Om = (float*)smem;
    __syncthreads();
    if (w == 1 || w == 3) {
        float* og = Om + (w >> 1) * 4096;
        #pragma unroll
        for (int qt = 0; qt < 2; qt++)
            #pragma unroll
            for (int dt = 0; dt < 2; dt++)
                #pragma unroll
                for (int i = 0; i < 16; i++) {
                    int row = (i & 3) + 8 * (i >> 2) + 4 * h;
                    og[(dt * 32 + row) * 64 + qt * 32 + col] = acc[qt][dt][i];
                }
    }
    __syncthreads();
    if (w == 0 || w == 2) {
        const float* og = Om + (w >> 1) * 4096;
        #pragma unroll
        for (int qt = 0; qt < 2; qt++)
            #pragma unroll
            for (int dt = 0; dt < 2; dt++)
                #pragma unroll
                for (int i = 0; i < 16; i++) {
                    int row = (i & 3) + 8 * (i >> 2) + 4 * h;
                    acc[qt][dt][i] += og[(dt * 32 + row) * 64 + qt * 32 + col];
                }
    }
    __syncthreads();
    if (w == 2) {
        #pragma unroll
        for (int qt = 0; qt < 2; qt++)
            #pragma unroll
            for (int dt = 0; dt < 2; dt++)
                #pragma unroll
                for (int i = 0; i < 16; i++) {
                    int row = (i & 3) + 8 * (i >> 2) + 4 * h;
                    Om[(dt * 32 + row) * 64 + qt * 32 + col] = acc[qt][dt][i];
                }
    }
    __syncthreads();
    if (w == 0) {
        #pragma unroll
        for (int qt = 0; qt < 2; qt++)
            #pragma unroll
            for (int dt = 0; dt < 2; dt++)
                #pragma unroll
                for (int i = 0; i < 16; i++) {
                    int row = (i & 3) + 8 * (i >> 2) + 4 * h;
                    acc[qt][dt][i] += Om[(dt * 32 + row) * 64 + qt * 32 + col];
                }
        const int bb = bh >> 3, hh = bh & 7;
        #pragma unroll
        for (int qt = 0; qt < 2; qt++) {
            float ls = Ls[0][qt][col] + Ls[1][qt][col]
                     + Ls[2][qt][col] + Ls[3][qt][col];
            const float inv = 1.0f / ls;
            f16* op = ctx + ((size_t)(bb * Lsz + q0 + qt * 32 + col)) * DIMsz
                          + hh * 64;
            #pragma unroll
            for (int dt = 0; dt < 2; dt++)
                #pragma unroll
                for (int r4 = 0; r4 < 4; r4++) {
                    f16x4 o;
                    o.x = (f16)(acc[qt][dt][4 * r4 + 0] * inv);
                    o.y = (f16)(acc[qt][dt][4 * r4 + 1] * inv);
                    o.z = (f16)(acc[qt][dt][4 * r4 + 2] * inv);
                    o.w = (f16)(acc[qt][dt][4 * r4 + 3] * inv);
                    *(f16x4*)(op + dt * 32 + 8 * r4 + 4 * h) = o;
                }
        }
    }
}

// ---------------- out-proj MFMA GEMM: out(fp32) = ctx @ wo^T -----------------
// 64x64 tiles, BK=128 (4 rounds, 8 barriers), grid (8, 128) = 1024 blocks.
__global__ __launch_bounds__(256) void gemm_out_f16(
    const f16* __restrict__ A, const f16* __restrict__ B,
    float* __restrict__ C)
{
    __shared__ f16 Ash[64 * 128];
    __shared__ f16 Bsh[64 * 128];
    const int tid = threadIdx.x;
    const int w = tid >> 6, lane = tid & 63;
    const int quad = lane >> 4, low = lane & 15;
    const int wm = w >> 1, wn = w & 1;
    const int m0 = blockIdx.y * 64, n0 = blockIdx.x * 64;

    f32x4 acc[2][2];
    #pragma unroll
    for (int i = 0; i < 2; i++)
        #pragma unroll
        for (int j = 0; j < 2; j++) acc[i][j] = (f32x4){0.f, 0.f, 0.f, 0.f};

    #pragma unroll 1
    for (int k0 = 0; k0 < DIMsz; k0 += 128) {
        __syncthreads();
        #pragma unroll
        for (int j = 0; j < 4; j++) {
            int t = j * 256 + tid;
            int r = t >> 4, g = t & 15;                // 64 rows x 16 chunks
            int gc = (g ^ (r & 15)) * 8;
            char* lb = (char*)Ash + (j * 256 + w * 64) * 16;
            gl2lds16(A + (size_t)(m0 + r) * DIMsz + k0 + gc, lb);
            char* lb2 = (char*)Bsh + (j * 256 + w * 64) * 16;
            gl2lds16(B + (size_t)(n0 + r) * DIMsz + k0 + gc, lb2);
        }
        __syncthreads();

        #pragma unroll
        for (int ks2 = 0; ks2 < 4; ks2++) {
            f16x8 af[2], bf[2];
            #pragma unroll
            for (int mt = 0; mt < 2; mt++) {
                int ar = wm * 32 + mt * 16 + low;
                int c = ks2 * 4 + quad;
                af[mt] = *(const f16x8*)&Ash[ar * 128 + ((c ^ (ar & 15)) << 3)];
            }
            #pragma unroll
            for (int nt = 0; nt < 2; nt++) {
                int br = wn * 32 + nt * 16 + low;
                int c = ks2 * 4 + quad;
                bf[nt] = *(const f16x8*)&Bsh[br * 128 + ((c ^ (br & 15)) << 3)];
            }
            #pragma unroll
            for (int mt = 0; mt < 2; mt++)
                #pragma unroll
                for (int nt = 0; nt < 2; nt++)
                    acc[mt][nt] = __builtin_amdgcn_mfma_f32_16x16x32_f16(
                        af[mt], bf[nt], acc[mt][nt], 0, 0, 0);
        }
    }

    #pragma unroll
    for (int mt = 0; mt < 2; mt++)
        #pragma unroll
        for (int r = 0; r < 4; r++) {
            int m = m0 + wm * 32 + mt * 16 + quad * 4 + r;
            #pragma unroll
            for (int nt = 0; nt < 2; nt++) {
                int n = n0 + wn * 32 + nt * 16 + low;
                C[(size_t)m * DIMsz + n] = acc[mt][nt][r];
            }
        }
}

extern "C" void kernel_launch(void* const* d_in, const int* in_sizes, int n_in,
                              void* d_out, int out_size, void* d_ws, size_t ws_size,
                              hipStream_t stream) {
    const float* x  = (const float*)d_in[0];
    const float* wq = (const float*)d_in[1];
    const float* wk = (const float*)d_in[2];
    const float* wv = (const float*)d_in[3];
    const float* wo = (const float*)d_in[4];
    float* out = (float*)d_out;

    const size_t NTOK = (size_t)Bsz * Lsz;   // 8192
    const size_t XSZ  = NTOK * DIMsz;        // 4,194,304

    f16* xh   = (f16*)d_ws;                  // 8 MB
    f16* w3h  = xh + XSZ;                    // 1.5 MB  [1536][512]
    f16* woh  = w3h + 3 * 262144;            // 0.5 MB
    f16* qh   = woh + 262144;                // 8 MB [bh][l][d] (scale*log2e)
    f16* kh   = qh + XSZ;                    // 8 MB [bh][l][d]
    f16* vth  = kh + XSZ;                    // 8 MB [bh][d][l]
    f16* ctxh = vth + XSZ;                   // 8 MB [b*l][512]

    pack_f16<<<5120, 256, 0, stream>>>(x, wq, wk, wv, wo, xh, w3h, woh);

    dim3 g1(1536 / 128, NTOK / 128);         // (12, 64)
    gemm_qkv_f16<<<g1, 256, 0, stream>>>(xh, w3h, qh, kh, vth);

    dim3 g2(Bsz * Hsz, Lsz / 64);            // (32 bh, 32 qb) — bh fastest
    attn_mfma<<<g2, 256, 0, stream>>>(qh, kh, vth, ctxh);

    dim3 g3(DIMsz / 64, NTOK / 64);          // (8, 128)
    gemm_out_f16<<<g3, 256, 0, stream>>>(ctxh, woh, out);
}

// Round 17
// 171.559 us; speedup vs baseline: 1.8264x; 1.8264x over previous
//
#include <hip/hip_runtime.h>
#include <hip/hip_bf16.h>

// B=4, L=2048, DIM=512, H=8, D=64, fp32 in/out.
// pack fp32->fp16 (log2e folded into wq) -> fused QKV MFMA GEMM (BK=64, V^T
// via in-LDS transpose epilogue) -> 32x32x16-MFMA flash attn (64q/wave,
// 4-way key-split, K-frags DIRECT FROM GLOBAL/L2, V double-buffered 2x16KB
// [1 barrier/round], permlane32_swap P-transform, fdot2 lsum) -> out GEMM.
// NOTE: global_load_lds imm offset applies to the GLOBAL address only.
// NOTE: NEVER set launch_bounds waves below the accumulator VGPR floor —
// r16's (256,4) capped VGPRs at 64 < acc(64)+qf(32)+kf(16) -> 450 MB of
// scratch spill traffic, 3.5x regression.

#define Bsz 4
#define Lsz 2048
#define DIMsz 512
#define Hsz 8
#define Dsz 64

typedef _Float16 f16;
typedef __attribute__((ext_vector_type(8))) _Float16 f16x8;
typedef __attribute__((ext_vector_type(4))) _Float16 f16x4;
typedef __attribute__((ext_vector_type(2))) __fp16 fp16x2;  // builtin ret type
typedef __attribute__((ext_vector_type(4))) float f32x4;
typedef __attribute__((ext_vector_type(16))) float f32x16;
typedef unsigned int u32;
typedef __attribute__((ext_vector_type(2))) unsigned int u32x2;

#if __has_builtin(__builtin_amdgcn_exp2f)
#define EXP2(x) __builtin_amdgcn_exp2f(x)
#else
#define EXP2(x) __expf(0.6931471805599453f * (x))
#endif

__device__ __forceinline__ u32 pack2(float a, float b) {
#if __has_builtin(__builtin_amdgcn_cvt_pkrtz)
    fp16x2 h = __builtin_amdgcn_cvt_pkrtz(a, b);
    return __builtin_bit_cast(u32, h);
#else
    fp16x2 h; h.x = (__fp16)a; h.y = (__fp16)b;
    return __builtin_bit_cast(u32, h);
#endif
}

// lsum += p0 + p1 from a packed f16 pair (v_dot2_f32_f16 with ones).
__device__ __forceinline__ float addpair(u32 p, float c) {
#if __has_builtin(__builtin_amdgcn_fdot2)
    fp16x2 ones; ones.x = (__fp16)1.0f; ones.y = (__fp16)1.0f;
    return __builtin_amdgcn_fdot2(__builtin_bit_cast(fp16x2, p), ones, c, false);
#else
    fp16x2 h = __builtin_bit_cast(fp16x2, p);
    return c + (float)h.x + (float)h.y;
#endif
}

// Cross-half exchange for the 32x32 C->B P-transform.
#if __has_builtin(__builtin_amdgcn_permlane32_swap)
__device__ __forceinline__ void plswap(u32& a, u32& b) {
    u32x2 r = __builtin_amdgcn_permlane32_swap(a, b, false, false);
    a = r.x; b = r.y;
}
#else
__device__ __forceinline__ void plswap(u32& a, u32& b) {
    u32 sa = (u32)__shfl_xor((int)a, 32);
    u32 sb = (u32)__shfl_xor((int)b, 32);
    bool hi = (threadIdx.x & 32) != 0;
    u32 na = hi ? sb : a;
    u32 nb = hi ? b : sa;
    a = na; b = nb;
}
#endif

__device__ __forceinline__ void gl2lds16(const void* g, void* l) {
    __builtin_amdgcn_global_load_lds(
        (const __attribute__((address_space(1))) u32*)g,
        (__attribute__((address_space(3))) u32*)l, 16, 0, 0);
}

// ---------------- pack: fp32 -> fp16 ----------------------------------------
__global__ __launch_bounds__(256) void pack_f16(
    const float* __restrict__ x, const float* __restrict__ wq,
    const float* __restrict__ wk, const float* __restrict__ wv,
    const float* __restrict__ wo,
    f16* __restrict__ xh, f16* __restrict__ w3h, f16* __restrict__ woh)
{
    int bx = blockIdx.x, seg, blk;
    if (bx < 4096) { seg = 0; blk = bx; }
    else { seg = 1 + ((bx - 4096) >> 8); blk = (bx - 4096) & 255; }
    const float* s; f16* d; float sc = 1.0f;
    switch (seg) {
        case 0: s = x;  d = xh;            break;
        case 1: s = wq; d = w3h;           sc = 0.18033688011112042f; break;
        case 2: s = wk; d = w3h + 262144;  break;
        case 3: s = wv; d = w3h + 524288;  break;
        default: s = wo; d = woh;          break;
    }
    int i = (blk * 256 + threadIdx.x) * 4;
    float4 v = *(const float4*)(s + i);
    f16x4 o;
    o.x = (f16)(v.x * sc); o.y = (f16)(v.y * sc);
    o.z = (f16)(v.z * sc); o.w = (f16)(v.w * sc);
    *(f16x4*)(d + i) = o;
}

// ---------------- fused QKV MFMA GEMM (BK=64) --------------------------------
__global__ __launch_bounds__(256) void gemm_qkv_f16(
    const f16* __restrict__ A, const f16* __restrict__ B,
    f16* __restrict__ qh, f16* __restrict__ kh, f16* __restrict__ vth)
{
    __shared__ __align__(16) char smem[32768];   // A 16K | B 16K ; Tv reuse
    f16* Ash = (f16*)smem;
    f16* Bsh = (f16*)(smem + 16384);

    const int tid = threadIdx.x;
    const int w = tid >> 6, lane = tid & 63;
    const int quad = lane >> 4, low = lane & 15;
    const int wm = w >> 1, wn = w & 1;
    const int m0 = blockIdx.y * 128, n0 = blockIdx.x * 128;

    f32x4 acc[4][4];
    #pragma unroll
    for (int i = 0; i < 4; i++)
        #pragma unroll
        for (int j = 0; j < 4; j++) acc[i][j] = (f32x4){0.f, 0.f, 0.f, 0.f};

    #pragma unroll 1
    for (int k0 = 0; k0 < DIMsz; k0 += 64) {
        __syncthreads();
        #pragma unroll
        for (int j = 0; j < 4; j++) {
            int t = j * 256 + tid;
            int r = t >> 3, g = t & 7;                 // 128 rows x 8 chunks
            int gc = (g ^ (r & 7)) * 8;
            char* lb = (char*)Ash + (j * 256 + w * 64) * 16;
            gl2lds16(A + (size_t)(m0 + r) * DIMsz + k0 + gc, lb);
            char* lb2 = (char*)Bsh + (j * 256 + w * 64) * 16;
            gl2lds16(B + (size_t)(n0 + r) * DIMsz + k0 + gc, lb2);
        }
        __syncthreads();

        #pragma unroll
        for (int ks2 = 0; ks2 < 2; ks2++) {
            f16x8 af[4], bf[4];
            #pragma unroll
            for (int mt = 0; mt < 4; mt++) {
                int ar = wm * 64 + mt * 16 + low;
                int c = ks2 * 4 + quad;
                af[mt] = *(const f16x8*)&Ash[ar * 64 + ((c ^ (ar & 7)) << 3)];
            }
            #pragma unroll
            for (int nt = 0; nt < 4; nt++) {
                int br = wn * 64 + nt * 16 + low;
                int c = ks2 * 4 + quad;
                bf[nt] = *(const f16x8*)&Bsh[br * 64 + ((c ^ (br & 7)) << 3)];
            }
            #pragma unroll
            for (int mt = 0; mt < 4; mt++)
                #pragma unroll
                for (int nt = 0; nt < 4; nt++)
                    acc[mt][nt] = __builtin_amdgcn_mfma_f32_16x16x32_f16(
                        af[mt], bf[nt], acc[mt][nt], 0, 0, 0);
        }
    }

    const int proj = n0 >> 9;                 // uniform per block
    if (proj < 2) {
        f16* dst = (proj == 0) ? qh : kh;
        #pragma unroll
        for (int nt = 0; nt < 4; nt++) {
            int n = n0 + wn * 64 + nt * 16 + low;
            int c = n & 511, h = c >> 6, d = c & 63;
            #pragma unroll
            for (int mt = 0; mt < 4; mt++)
                #pragma unroll
                for (int r = 0; r < 4; r++) {
                    int m = m0 + wm * 64 + mt * 16 + quad * 4 + r;
                    int b_ = m >> 11, l = m & (Lsz - 1);
                    size_t bh = (size_t)(b_ * Hsz + h);
                    dst[(bh * Lsz + l) * Dsz + d] = (f16)acc[mt][nt][r];
                }
        }
    } else {
        // v: transpose per head through LDS, then coalesced stores
        const int hb = (n0 & 511) >> 6;
        f16* Tv = (f16*)smem;                 // [64 d][136]
        const int b_ = m0 >> 11, l0 = m0 & (Lsz - 1);
        #pragma unroll 1
        for (int hs = 0; hs < 2; hs++) {
            __syncthreads();
            if (wn == hs) {
                #pragma unroll
                for (int nt = 0; nt < 4; nt++) {
                    int d = nt * 16 + low;
                    #pragma unroll
                    for (int mt = 0; mt < 4; mt++)
                        #pragma unroll
                        for (int r = 0; r < 4; r++) {
                            int l = wm * 64 + mt * 16 + quad * 4 + r;
                            Tv[d * 136 + l] = (f16)acc[mt][nt][r];
                        }
                }
            }
            __syncthreads();
            int d = tid >> 2, seg = tid & 3;
            size_t bh = (size_t)(b_ * Hsz + hb + hs);
            f16* dstp = vth + (bh * 64 + d) * (size_t)Lsz + l0 + seg * 32;
            const f16* srcp = Tv + d * 136 + seg * 32;
            #pragma unroll
            for (int j = 0; j < 4; j++)
                *(f16x8*)(dstp + j * 8) = *(const f16x8*)(srcp + j * 8);
        }
    }
}

// ---------------- MFMA flash attention ---------------------------------------
// grid (B*H=32 fastest -> XCD locality, L/64=32), block 256 = 4 waves = 64 q.
// Wave w owns keys w*32..+31 of each 128-key round vs all 64 q. K A-frags
// load DIRECTLY from global (per-head K = 256 KB, XCD-L2-resident); V is
// staged via DMA into a 2x16KB double buffer -> one barrier per round.
// 4-way split-K merge at the end through the reused V buffers.
// launch_bounds (256,2): allocator budget 256 VGPRs (no spill); actual use
// ~112 <= 128 keeps 4-waves/SIMD hardware occupancy eligible.
__global__ __launch_bounds__(256, 2) void attn_mfma(
    const f16* __restrict__ q, const f16* __restrict__ k,
    const f16* __restrict__ vt, f16* __restrict__ ctx)
{
    __shared__ __align__(16) char smem[32768];   // V dbuf 2x16KB ; O-merge
    __shared__ float Ls[4][2][32];               // per-wave lsum partials

    const int tid = threadIdx.x;
    const int w = tid >> 6, lane = tid & 63;
    const int col = lane & 31;
    const int h = lane >> 5;
    const int bh = blockIdx.x;        // fastest -> heads spread across XCDs
    const int qb = blockIdx.y;
    const int q0 = qb * 64;
    const size_t kvb = (size_t)bh * Lsz;

    // Q B-frags for 2 q-tiles: B[k=d][n=q], lane n=col, k = s*16 + h*8 + j
    f16x8 qf[2][4];
    #pragma unroll
    for (int qt = 0; qt < 2; qt++)
        #pragma unroll
        for (int s = 0; s < 4; s++)
            qf[qt][s] = *(const f16x8*)(q + (kvb + q0 + qt * 32 + col) * Dsz
                                          + s * 16 + h * 8);

    // K global frag base: row w*32+col, f16-col h*8; bumped +128 rows/round
    const f16* kgp = k + (kvb + w * 32 + col) * Dsz + h * 8;

    // V staging source (lane-specific, bumped per round)
    const f16* vp;
    {
        int rv = tid >> 4, gv = tid & 15;         // vp covers rows 0..15
        vp = vt + ((size_t)bh * Dsz + rv) * Lsz + ((gv ^ (rv & 15)) << 3);
    }

    // per-buffer LDS pointers (staging dests + frag reads)
    char* vl[2];
    const f16* vfp[2][2][2];
    #pragma unroll
    for (int b = 0; b < 2; b++) {
        f16* Vs = (f16*)(smem + b * 16384);
        vl[b] = (char*)Vs + (w * 64) * 16;
        #pragma unroll
        for (int dt = 0; dt < 2; dt++)
            #pragma unroll
            for (int ks = 0; ks < 2; ks++) {
                int rv = dt * 32 + col, cv = w * 4 + ks * 2 + h;
                vfp[b][dt][ks] = Vs + rv * 128 + ((cv ^ (rv & 15)) << 3);
            }
    }

    f32x16 acc[2][2];                 // O^T partial [qt][dt], cols = q
    #pragma unroll
    for (int qt = 0; qt < 2; qt++)
        #pragma unroll
        for (int dt = 0; dt < 2; dt++)
            #pragma unroll
            for (int i = 0; i < 16; i++) acc[qt][dt][i] = 0.f;
    float lsum[2] = {0.f, 0.f};

    const int drnd_i = qb >> 1;                   // round containing the diag
    const int dqt = w - (qb & 1) * 2;             // qt this wave diag-masks

    // prologue: stage V round 0 into buf 0
    gl2lds16(vp,            vl[0]);
    gl2lds16(vp + 16 * Lsz, vl[0] + 4096);
    gl2lds16(vp + 32 * Lsz, vl[0] + 8192);
    gl2lds16(vp + 48 * Lsz, vl[0] + 12288);
    vp += 128;
    __syncthreads();

    int b = 0;
    #pragma unroll 1
    for (int r = 0; r < 16; r++) {
        // K frags for this round, straight from global/L2
        f16x8 kf[4];
        #pragma unroll
        for (int s = 0; s < 4; s++)
            kf[s] = *(const f16x8*)(kgp + s * 16);
        kgp += 128 * Dsz;

        // stage next round's V into the other buffer (overlaps compute)
        if (r < 15) {
            char* vnl = vl[b ^ 1];
            gl2lds16(vp,            vnl);
            gl2lds16(vp + 16 * Lsz, vnl + 4096);
            gl2lds16(vp + 32 * Lsz, vnl + 8192);
            gl2lds16(vp + 48 * Lsz, vnl + 12288);
            vp += 128;
        }

        // ---- S^T: A = own 32 K rows, B = both q-tiles; 4 k-steps over d ----
        f32x16 st[2];
        #pragma unroll
        for (int i = 0; i < 16; i++) { st[0][i] = 0.f; st[1][i] = 0.f; }
        #pragma unroll
        for (int s = 0; s < 4; s++) {
            st[0] = __builtin_amdgcn_mfma_f32_32x32x16_f16(kf[s], qf[0][s], st[0], 0, 0, 0);
            st[1] = __builtin_amdgcn_mfma_f32_32x32x16_f16(kf[s], qf[1][s], st[1], 0, 0, 0);
        }

        // ---- softmax numerators + C->B transform per q-tile ----
        union { u32 u[4]; f16x8 v; } pf[2][2];
        const bool drnd = (r == drnd_i);
        #pragma unroll
        for (int qt = 0; qt < 2; qt++) {
            float pv[16];
            #pragma unroll
            for (int i = 0; i < 16; i++) pv[i] = EXP2(st[qt][i]);
            if (drnd && qt == dqt) {
                #pragma unroll
                for (int i = 0; i < 16; i++) {
                    int row = (i & 3) + 8 * (i >> 2) + 4 * h;
                    pv[i] = (row == col) ? 0.f : pv[i];
                }
            }
            u32 P2[8];
            #pragma unroll
            for (int j = 0; j < 8; j++) {
                P2[j] = pack2(pv[2 * j], pv[2 * j + 1]);
                lsum[qt] = addpair(P2[j], lsum[qt]);
            }
            plswap(P2[0], P2[2]); plswap(P2[1], P2[3]);
            plswap(P2[4], P2[6]); plswap(P2[5], P2[7]);
            #pragma unroll
            for (int jj = 0; jj < 4; jj++) {
                pf[qt][0].u[jj] = P2[jj];
                pf[qt][1].u[jj] = P2[4 + jj];
            }
        }

        // ---- O^T += V^T . P over own 32 keys (V frags reused across qt) ----
        #pragma unroll
        for (int dt = 0; dt < 2; dt++)
            #pragma unroll
            for (int ks = 0; ks < 2; ks++) {
                f16x8 vf = *(const f16x8*)vfp[b][dt][ks];
                acc[0][dt] = __builtin_amdgcn_mfma_f32_32x32x16_f16(
                    vf, pf[0][ks].v, acc[0][dt], 0, 0, 0);
                acc[1][dt] = __builtin_amdgcn_mfma_f32_32x32x16_f16(
                    vf, pf[1][ks].v, acc[1][dt], 0, 0, 0);
            }

        __syncthreads();   // drains next-round DMA; all readers done with buf b
        b ^= 1;
    }

    // lsum: reduce over half-wave, publish per-wave partial
    #pragma unroll
    for (int qt = 0; qt < 2; qt++) {
        lsum[qt] += __shfl_xor(lsum[qt], 32);
        if (h == 0) Ls[w][qt][col] = lsum[qt];
    }

    // ---- 4-way split-K merge via reused V buffers (2 x 16KB slots) ----
    float* Om = (float*)smem;
    __syncthreads();
    if (w == 1 || w == 3) {
        float* og = Om + (w >> 1) * 4096;
        #pragma unroll
        for (int qt = 0; qt < 2; qt++)
            #pragma unroll
            for (int dt = 0; dt < 2; dt++)
                #pragma unroll
                for (int i = 0; i < 16; i++) {
                    int row = (i & 3) + 8 * (i >> 2) + 4 * h;
                    og[(dt * 32 + row) * 64 + qt * 32 + col] = acc[qt][dt][i];
                }
    }
    __syncthreads();
    if (w == 0 || w == 2) {
        const float* og = Om + (w >> 1) * 4096;
        #pragma unroll
        for (int qt = 0; qt < 2; qt++)
            #pragma unroll
            for (int dt = 0; dt < 2; dt++)
                #pragma unroll
                for (int i = 0; i < 16; i++) {
                    int row = (i & 3) + 8 * (i >> 2) + 4 * h;
                    acc[qt][dt][i] += og[(dt * 32 + row) * 64 + qt * 32 + col];
                }
    }
    __syncthreads();
    if (w == 2) {
        #pragma unroll
        for (int qt = 0; qt < 2; qt++)
            #pragma unroll
            for (int dt = 0; dt < 2; dt++)
                #pragma unroll
                for (int i = 0; i < 16; i++) {
                    int row = (i & 3) + 8 * (i >> 2) + 4 * h;
                    Om[(dt * 32 + row) * 64 + qt * 32 + col] = acc[qt][dt][i];
                }
    }
    __syncthreads();
    if (w == 0) {
        #pragma unroll
        for (int qt = 0; qt < 2; qt++)
            #pragma unroll
            for (int dt = 0; dt < 2; dt++)
                #pragma unroll
                for (int i = 0; i < 16; i++) {
                    int row = (i & 3) + 8 * (i >> 2) + 4 * h;
                    acc[qt][dt][i] += Om[(dt * 32 + row) * 64 + qt * 32 + col];
                }
        const int bb = bh >> 3, hh = bh & 7;
        #pragma unroll
        for (int qt = 0; qt < 2; qt++) {
            float ls = Ls[0][qt][col] + Ls[1][qt][col]
                     + Ls[2][qt][col] + Ls[3][qt][col];
            const float inv = 1.0f / ls;
            f16* op = ctx + ((size_t)(bb * Lsz + q0 + qt * 32 + col)) * DIMsz
                          + hh * 64;
            #pragma unroll
            for (int dt = 0; dt < 2; dt++)
                #pragma unroll
                for (int r4 = 0; r4 < 4; r4++) {
                    f16x4 o;
                    o.x = (f16)(acc[qt][dt][4 * r4 + 0] * inv);
                    o.y = (f16)(acc[qt][dt][4 * r4 + 1] * inv);
                    o.z = (f16)(acc[qt][dt][4 * r4 + 2] * inv);
                    o.w = (f16)(acc[qt][dt][4 * r4 + 3] * inv);
                    *(f16x4*)(op + dt * 32 + 8 * r4 + 4 * h) = o;
                }
        }
    }
}

// ---------------- out-proj MFMA GEMM: out(fp32) = ctx @ wo^T -----------------
// 64x64 tiles, BK=128 (4 rounds, 8 barriers), grid (8, 128) = 1024 blocks.
__global__ __launch_bounds__(256) void gemm_out_f16(
    const f16* __restrict__ A, const f16* __restrict__ B,
    float* __restrict__ C)
{
    __shared__ f16 Ash[64 * 128];
    __shared__ f16 Bsh[64 * 128];
    const int tid = threadIdx.x;
    const int w = tid >> 6, lane = tid & 63;
    const int quad = lane >> 4, low = lane & 15;
    const int wm = w >> 1, wn = w & 1;
    const int m0 = blockIdx.y * 64, n0 = blockIdx.x * 64;

    f32x4 acc[2][2];
    #pragma unroll
    for (int i = 0; i < 2; i++)
        #pragma unroll
        for (int j = 0; j < 2; j++) acc[i][j] = (f32x4){0.f, 0.f, 0.f, 0.f};

    #pragma unroll 1
    for (int k0 = 0; k0 < DIMsz; k0 += 128) {
        __syncthreads();
        #pragma unroll
        for (int j = 0; j < 4; j++) {
            int t = j * 256 + tid;
            int r = t >> 4, g = t & 15;                // 64 rows x 16 chunks
            int gc = (g ^ (r & 15)) * 8;
            char* lb = (char*)Ash + (j * 256 + w * 64) * 16;
            gl2lds16(A + (size_t)(m0 + r) * DIMsz + k0 + gc, lb);
            char* lb2 = (char*)Bsh + (j * 256 + w * 64) * 16;
            gl2lds16(B + (size_t)(n0 + r) * DIMsz + k0 + gc, lb2);
        }
        __syncthreads();

        #pragma unroll
        for (int ks2 = 0; ks2 < 4; ks2++) {
            f16x8 af[2], bf[2];
            #pragma unroll
            for (int mt = 0; mt < 2; mt++) {
                int ar = wm * 32 + mt * 16 + low;
                int c = ks2 * 4 + quad;
                af[mt] = *(const f16x8*)&Ash[ar * 128 + ((c ^ (ar & 15)) << 3)];
            }
            #pragma unroll
            for (int nt = 0; nt < 2; nt++) {
                int br = wn * 32 + nt * 16 + low;
                int c = ks2 * 4 + quad;
                bf[nt] = *(const f16x8*)&Bsh[br * 128 + ((c ^ (br & 15)) << 3)];
            }
            #pragma unroll
            for (int mt = 0; mt < 2; mt++)
                #pragma unroll
                for (int nt = 0; nt < 2; nt++)
                    acc[mt][nt] = __builtin_amdgcn_mfma_f32_16x16x32_f16(
                        af[mt], bf[nt], acc[mt][nt], 0, 0, 0);
        }
    }

    #pragma unroll
    for (int mt = 0; mt < 2; mt++)
        #pragma unroll
        for (int r = 0; r < 4; r++) {
            int m = m0 + wm * 32 + mt * 16 + quad * 4 + r;
            #pragma unroll
            for (int nt = 0; nt < 2; nt++) {
                int n = n0 + wn * 32 + nt * 16 + low;
                C[(size_t)m * DIMsz + n] = acc[mt][nt][r];
            }
        }
}

extern "C" void kernel_launch(void* const* d_in, const int* in_sizes, int n_in,
                              void* d_out, int out_size, void* d_ws, size_t ws_size,
                              hipStream_t stream) {
    const float* x  = (const float*)d_in[0];
    const float* wq = (const float*)d_in[1];
    const float* wk = (const float*)d_in[2];
    const float* wv = (const float*)d_in[3];
    const float* wo = (const float*)d_in[4];
    float* out = (float*)d_out;

    const size_t NTOK = (size_t)Bsz * Lsz;   // 8192
    const size_t XSZ  = NTOK * DIMsz;        // 4,194,304

    f16* xh   = (f16*)d_ws;                  // 8 MB
    f16* w3h  = xh + XSZ;                    // 1.5 MB  [1536][512]
    f16* woh  = w3h + 3 * 262144;            // 0.5 MB
    f16* qh   = woh + 262144;                // 8 MB [bh][l][d] (scale*log2e)
    f16* kh   = qh + XSZ;                    // 8 MB [bh][l][d]
    f16* vth  = kh + XSZ;                    // 8 MB [bh][d][l]
    f16* ctxh = vth + XSZ;                   // 8 MB [b*l][512]

    pack_f16<<<5120, 256, 0, stream>>>(x, wq, wk, wv, wo, xh, w3h, woh);

    dim3 g1(1536 / 128, NTOK / 128);         // (12, 64)
    gemm_qkv_f16<<<g1, 256, 0, stream>>>(xh, w3h, qh, kh, vth);

    dim3 g2(Bsz * Hsz, Lsz / 64);            // (32 bh, 32 qb) — bh fastest
    attn_mfma<<<g2, 256, 0, stream>>>(qh, kh, vth, ctxh);

    dim3 g3(DIMsz / 64, NTOK / 64);          // (8, 128)
    gemm_out_f16<<<g3, 256, 0, stream>>>(ctxh, woh, out);
}